// Round 8
// baseline (280.803 us; speedup 1.0000x reference)
//
#include <hip/hip_runtime.h>
#include <math.h>

#define BB 64
#define QQ 32
#define DD 4096
#define EE 300
#define EPAD 320         // qn k-padded with zeros to 320 (10 chunks of 32)
#define NB 30
#define WD 64            // doc rows per wave
#define TDB 256          // doc rows per block (4 waves)
#define NDT (DD/TDB)     // 16
#define NCH 10           // K-chunks of 32 floats

typedef __attribute__((ext_vector_type(8))) short short8v;   // 8 bf16 = 1 MFMA frag
typedef __attribute__((ext_vector_type(4))) float f32x4;

// RNE float->bf16 (bit pattern), and bf16->float
static __device__ __forceinline__ unsigned short f2bf(float x) {
    unsigned int u = __builtin_bit_cast(unsigned int, x);
    u = (u + 0x7FFFu + ((u >> 16) & 1u)) >> 16;
    return (unsigned short)u;
}
static __device__ __forceinline__ float bf2f(unsigned short h) {
    return __builtin_bit_cast(float, (unsigned int)h << 16);
}

// ---------------- prep: normalize query, split to bf16 hi/lo, gate logits, zero hist ----
__global__ __launch_bounds__(64) void drmm_prep(const float* __restrict__ query,
                                                const float* __restrict__ Wg,
                                                const float* __restrict__ bg,
                                                unsigned short* __restrict__ qh,
                                                unsigned short* __restrict__ ql,
                                                float* __restrict__ glog,
                                                int* __restrict__ ghist) {
    const int row  = blockIdx.x;          // b*32+q
    const int lane = threadIdx.x;         // 0..63
    if (lane < NB) ghist[(size_t)row * NB + lane] = 0;   // replaces the memset dispatch
    const float* src = query + (size_t)row * EE;
    float ss = 0.f;
    for (int e = lane; e < EE; e += 64) { float x = src[e]; ss += x * x; }
    for (int o = 1; o < 64; o <<= 1) ss += __shfl_xor(ss, o);
    const float inv = 1.0f / sqrtf(ss);
    float gd = 0.f;
    #pragma unroll
    for (int it = 0; it < 5; ++it) {      // 5*64 = 320 = EPAD
        int e = it * 64 + lane;
        float x = (e < EE) ? src[e] * inv : 0.f;
        unsigned short h = f2bf(x);
        float lo = x - bf2f(h);
        qh[(size_t)row * EPAD + e] = h;
        ql[(size_t)row * EPAD + e] = f2bf(lo);
        if (e < EE) gd += x * Wg[e];
    }
    for (int o = 1; o < 64; o <<= 1) gd += __shfl_xor(gd, o);
    if (lane == 0) glog[row] = gd + bg[0];
}

// issue the 8 doc loads for chunk c into v (prefetch registers)
static __device__ __forceinline__ void load_doc(const float* __restrict__ drow0,
                                                int kw, int c, f32x4 (&v)[4][2]) {
    const int kb = c * 32 + kw;
    const int k1 = (kb     < EE) ? kb     : 0;   // pad windows redirected in-bounds;
    const int k2 = (kb + 4 < EE) ? kb + 4 : 0;   // products hit qn pad zeros anyway
    #pragma unroll
    for (int t = 0; t < 4; ++t) {
        const float* rp = drow0 + (size_t)t * 16 * EE;
        v[t][0] = *(const f32x4*)(rp + k1);
        v[t][1] = *(const f32x4*)(rp + k2);
    }
}

// convert + MFMA + ssq for chunk c using already-loaded v
static __device__ __forceinline__ void body(int c, int kw, int nqt,
                                            const unsigned short* __restrict__ qhb,
                                            const unsigned short* __restrict__ qlb,
                                            const f32x4 (&v)[4][2],
                                            f32x4 (&acc)[2][4], float (&ssq)[4]) {
    short8v ah0 = *(const short8v*)(qhb + c * 32);
    short8v al0 = *(const short8v*)(qlb + c * 32);
    short8v ah1 = {}, al1 = {};
    if (nqt > 1) {
        ah1 = *(const short8v*)(qhb + 16 * EPAD + c * 32);
        al1 = *(const short8v*)(qlb + 16 * EPAD + c * 32);
    }
    const int kb = c * 32 + kw;
    const bool r1 = (kb < EE), r2 = (kb + 4 < EE);   // real (non-pad) windows

    #pragma unroll
    for (int t = 0; t < 4; ++t) {
        const f32x4 v0 = v[t][0], v1 = v[t][1];
        if (r1) ssq[t] += v0.x * v0.x + v0.y * v0.y + v0.z * v0.z + v0.w * v0.w;
        if (r2) ssq[t] += v1.x * v1.x + v1.y * v1.y + v1.z * v1.z + v1.w * v1.w;

        short8v bhi, blo;
        #pragma unroll
        for (int j = 0; j < 4; ++j) {
            unsigned short h0 = f2bf(v0[j]);
            unsigned short h1 = f2bf(v1[j]);
            bhi[j]     = (short)h0;
            bhi[j + 4] = (short)h1;
            blo[j]     = (short)f2bf(v0[j] - bf2f(h0));
            blo[j + 4] = (short)f2bf(v1[j] - bf2f(h1));
        }
        acc[0][t] = __builtin_amdgcn_mfma_f32_16x16x32_bf16(ah0, bhi, acc[0][t], 0, 0, 0);
        acc[0][t] = __builtin_amdgcn_mfma_f32_16x16x32_bf16(ah0, blo, acc[0][t], 0, 0, 0);
        acc[0][t] = __builtin_amdgcn_mfma_f32_16x16x32_bf16(al0, bhi, acc[0][t], 0, 0, 0);
        if (nqt > 1) {
            acc[1][t] = __builtin_amdgcn_mfma_f32_16x16x32_bf16(ah1, bhi, acc[1][t], 0, 0, 0);
            acc[1][t] = __builtin_amdgcn_mfma_f32_16x16x32_bf16(ah1, blo, acc[1][t], 0, 0, 0);
            acc[1][t] = __builtin_amdgcn_mfma_f32_16x16x32_bf16(al1, bhi, acc[1][t], 0, 0, 0);
        }
    }
}

// ---------------- main: MFMA interaction + histogram ----------------
// 256 threads = 4 waves; wave wv owns doc rows [dt*256+wv*64, +64) as 4 tiles of 16.
// Register double-buffer: chunk c+1's 8 doc dwordx4 issued before chunk c's
// convert+MFMA (2-deep software pipeline, no LDS, no in-loop barriers).
__global__ __launch_bounds__(256, 4) void drmm_main(const float* __restrict__ doc,
                                                    const int* __restrict__ qlen,
                                                    const unsigned short* __restrict__ qh,
                                                    const unsigned short* __restrict__ ql,
                                                    int* __restrict__ ghist) {
    __shared__ int s_hist[QQ][32];        // 4 KB, padded rows

    const int b   = blockIdx.x >> 4;
    const int dt  = blockIdx.x & 15;
    const int len = qlen[b];
    if (len == 0) return;                 // hist stays zero for this b

    const int tid = threadIdx.x;
    const int wv  = tid >> 6;
    const int l15 = tid & 15;             // fragment row index
    const int l4  = (tid >> 4) & 3;       // k-group (0..3)
    const int kw  = l4 * 8;               // lane's k-offset within chunk
    const int nqt = (len > 16) ? 2 : 1;   // scalar: q-tiles needed

    for (int s = tid; s < QQ * 32; s += 256) ((int*)s_hist)[s] = 0;

    const float* drow0 = doc + (size_t)(b * DD + dt * TDB + wv * WD + l15) * EE;
    const unsigned short* qhb = qh + ((size_t)b * QQ + l15) * EPAD + kw;
    const unsigned short* qlb = ql + ((size_t)b * QQ + l15) * EPAD + kw;

    f32x4 acc[2][4];
    #pragma unroll
    for (int qt = 0; qt < 2; ++qt)
        #pragma unroll
        for (int t = 0; t < 4; ++t) acc[qt][t] = (f32x4){0.f, 0.f, 0.f, 0.f};
    float ssq[4] = {0.f, 0.f, 0.f, 0.f};

    f32x4 vA[4][2], vB[4][2];
    load_doc(drow0, kw, 0, vA);
    #pragma unroll
    for (int cc = 0; cc < NCH; cc += 2) {           // NCH even: cc+1 always valid
        load_doc(drow0, kw, cc + 1, vB);            // prefetch c+1 while computing c
        body(cc, kw, nqt, qhb, qlb, vA, acc, ssq);
        if (cc + 2 < NCH) load_doc(drow0, kw, cc + 2, vA);
        body(cc + 1, kw, nqt, qhb, qlb, vB, acc, ssq);
    }

    // full row-norms: combine the 4 k-group partials (lanes l, l^16, l^32)
    float rinv[4];
    #pragma unroll
    for (int t = 0; t < 4; ++t) {
        float s = ssq[t];
        s += __shfl_xor(s, 16);
        s += __shfl_xor(s, 32);
        rinv[t] = 1.0f / sqrtf(s);        // row (l15) of tile t
    }

    __syncthreads();                      // hist zeros visible before atomics

    // D layout (m89-verified): col = lane&15 (= d within tile), row = (lane>>4)*4 + reg (= q)
    #pragma unroll
    for (int qt = 0; qt < 2; ++qt) {
        #pragma unroll
        for (int r = 0; r < 4; ++r) {
            const int q = qt * 16 + l4 * 4 + r;
            if (q < len) {
                #pragma unroll
                for (int t = 0; t < 4; ++t) {
                    float sim = acc[qt][t][r] * rinv[t];
                    int bin = (int)floorf((sim + 1.0f) * 15.0f);
                    bin = bin < 0 ? 0 : (bin > 29 ? 29 : bin);
                    atomicAdd(&s_hist[q][bin], 1);
                }
            }
        }
    }
    __syncthreads();

    for (int s = tid; s < QQ * NB; s += 256) {
        const int q = s / NB, bin = s % NB;
        int tot = s_hist[q][bin];
        if (tot) atomicAdd(&ghist[((size_t)b * QQ + q) * NB + bin], tot);
    }
}

// ---------------- final: log1p + FFN + softmax gate + weighted sum ----------------
__global__ __launch_bounds__(64) void drmm_final(const int* __restrict__ ghist,
                                                 const float* __restrict__ glog,
                                                 const float* __restrict__ W1,
                                                 const float* __restrict__ b1,
                                                 const float* __restrict__ W2,
                                                 const float* __restrict__ b2,
                                                 const float* __restrict__ W3,
                                                 const float* __restrict__ b3,
                                                 float* __restrict__ out) {
    const int b = blockIdx.x;
    const int lane = threadIdx.x;         // lanes 0..31 carry q
    float z = 0.f, lg = -1e30f;
    if (lane < QQ) {
        const int* hrow = ghist + ((size_t)b * QQ + lane) * NB;
        float h[NB];
        #pragma unroll
        for (int v = 0; v < NB; ++v) h[v] = log1pf((float)hrow[v]);
        float t1[5];
        #pragma unroll
        for (int u = 0; u < 5; ++u) {
            float s = b1[u];
            #pragma unroll
            for (int v = 0; v < NB; ++v) s += W1[u * NB + v] * h[v];
            t1[u] = tanhf(s);
        }
        float s2 = b2[0];
        #pragma unroll
        for (int u = 0; u < 5; ++u) s2 += W2[u] * t1[u];
        z = tanhf(W3[0] * tanhf(s2) + b3[0]);
        lg = glog[b * QQ + lane];
    }
    float m = lg;
    for (int o = 16; o >= 1; o >>= 1) m = fmaxf(m, __shfl_xor(m, o));
    float e = (lane < QQ) ? expf(lg - m) : 0.f;
    float s = e;
    for (int o = 16; o >= 1; o >>= 1) s += __shfl_xor(s, o);
    float w = z * (e / s);
    for (int o = 16; o >= 1; o >>= 1) w += __shfl_xor(w, o);
    if (lane == 0) out[b] = w;
}

extern "C" void kernel_launch(void* const* d_in, const int* in_sizes, int n_in,
                              void* d_out, int out_size, void* d_ws, size_t ws_size,
                              hipStream_t stream) {
    const float* query = (const float*)d_in[0];
    const float* doc   = (const float*)d_in[1];
    const int*   qlen  = (const int*)d_in[2];
    const float* W1    = (const float*)d_in[3];
    const float* b1    = (const float*)d_in[4];
    const float* W2    = (const float*)d_in[5];
    const float* b2    = (const float*)d_in[6];
    const float* W3    = (const float*)d_in[7];
    const float* b3    = (const float*)d_in[8];
    const float* Wg    = (const float*)d_in[9];
    const float* bg    = (const float*)d_in[10];
    float* out = (float*)d_out;

    unsigned short* qh = (unsigned short*)d_ws;            // [2048][320] bf16 hi
    unsigned short* ql = qh + (size_t)BB * QQ * EPAD;      // [2048][320] bf16 lo
    float* glog = (float*)(ql + (size_t)BB * QQ * EPAD);   // [2048]
    int*   hist = (int*)(glog + BB * QQ);                  // [64][32][30]

    hipLaunchKernelGGL(drmm_prep, dim3(BB * QQ), dim3(64), 0, stream,
                       query, Wg, bg, qh, ql, glog, hist);
    hipLaunchKernelGGL(drmm_main, dim3(BB * NDT), dim3(256), 0, stream,
                       doc, qlen, qh, ql, hist);
    hipLaunchKernelGGL(drmm_final, dim3(BB), dim3(64), 0, stream,
                       hist, glog, W1, b1, W2, b2, W3, b3, out);
}

// Round 9
// 94.928 us; speedup vs baseline: 2.9581x; 2.9581x over previous
//
#include <hip/hip_runtime.h>
#include <math.h>

#define BB 64
#define QQ 32
#define DD 4096
#define EE 300
#define EPAD 320         // qn k-padded with zeros to 320 (10 chunks of 32)
#define NB 30
#define TDB 128          // doc rows per block
#define NDT (DD/TDB)     // 32
#define KC 32            // floats per K-chunk
#define NCH 10

typedef __attribute__((ext_vector_type(8))) short short8v;   // 8 bf16 = 1 MFMA frag
typedef __attribute__((ext_vector_type(4))) float f32x4;

// RNE float->bf16 (bit pattern), and bf16->float
static __device__ __forceinline__ unsigned short f2bf(float x) {
    unsigned int u = __builtin_bit_cast(unsigned int, x);
    u = (u + 0x7FFFu + ((u >> 16) & 1u)) >> 16;
    return (unsigned short)u;
}
static __device__ __forceinline__ float bf2f(unsigned short h) {
    return __builtin_bit_cast(float, (unsigned int)h << 16);
}

// ---------------- prep: normalize query, split to bf16 hi/lo, gate logits, zero hist ----
__global__ __launch_bounds__(64) void drmm_prep(const float* __restrict__ query,
                                                const float* __restrict__ Wg,
                                                const float* __restrict__ bg,
                                                unsigned short* __restrict__ qh,
                                                unsigned short* __restrict__ ql,
                                                float* __restrict__ glog,
                                                int* __restrict__ ghist) {
    const int row  = blockIdx.x;          // b*32+q
    const int lane = threadIdx.x;         // 0..63
    if (lane < NB) ghist[(size_t)row * NB + lane] = 0;   // replaces memset dispatch
    const float* src = query + (size_t)row * EE;
    float ss = 0.f;
    for (int e = lane; e < EE; e += 64) { float x = src[e]; ss += x * x; }
    for (int o = 1; o < 64; o <<= 1) ss += __shfl_xor(ss, o);
    const float inv = 1.0f / sqrtf(ss);
    float gd = 0.f;
    #pragma unroll
    for (int it = 0; it < 5; ++it) {      // 5*64 = 320 = EPAD
        int e = it * 64 + lane;
        float x = (e < EE) ? src[e] * inv : 0.f;
        unsigned short h = f2bf(x);
        float lo = x - bf2f(h);
        qh[(size_t)row * EPAD + e] = h;
        ql[(size_t)row * EPAD + e] = f2bf(lo);
        if (e < EE) gd += x * Wg[e];
    }
    for (int o = 1; o < 64; o <<= 1) gd += __shfl_xor(gd, o);
    if (lane == 0) glog[row] = gd + bg[0];
}

// ---------------- main: LDS-staged MFMA interaction + histogram ----------------
// 256 threads = 4 waves; wave wv owns doc rows [wv*32, wv*32+32) of the block's
// 128-row tile as 2 MFMA tiles of 16. Per 32-float chunk: doc (16 KB, swizzled
// slots) + qn hi/lo chunks (4 KB) staged via global_load_lds, double-buffered,
// counted vmcnt(5) (5 loads/thread/chunk), 2 barriers/chunk (R6-proven shape).
// Compute = R7-proven bf16 3-way-split MFMA. LDS 40,960 B -> 4 blocks/CU;
// in-flight ~80 KB/CU >> BW*latency. Hist aliases s_doc after the loop.
__global__ __launch_bounds__(256, 4) void drmm_main(const float* __restrict__ doc,
                                                    const int* __restrict__ qlen,
                                                    const unsigned short* __restrict__ qh,
                                                    const unsigned short* __restrict__ ql,
                                                    int* __restrict__ ghist) {
    __shared__ __align__(16) float s_doc[2][TDB * KC];          // 2 x 16 KB
    __shared__ __align__(16) unsigned short s_qh[2][QQ * KC];   // 2 x 2 KB
    __shared__ __align__(16) unsigned short s_ql[2][QQ * KC];   // 2 x 2 KB

    const int b   = blockIdx.x >> 5;
    const int dt  = blockIdx.x & 31;
    const int len = __builtin_amdgcn_readfirstlane(qlen[b]);
    if (len == 0) return;                 // hist stays zero (prep zeroed ghist)

    const int tid = threadIdx.x;
    const int wv  = tid >> 6;             // wave id (uniform)
    const int td  = tid & 63;
    const int l15 = tid & 15;             // fragment row index
    const int l4  = (tid >> 4) & 3;       // k-window (0..3), 8 floats each
    const int nqt = (len > 16) ? 2 : 1;   // q-tiles needed (scalar)

    const float* docb = doc + ((size_t)b * DD + dt * TDB) * EE;
    const unsigned short* qhb = qh + (size_t)b * QQ * EPAD;
    const unsigned short* qlb = ql + (size_t)b * QQ * EPAD;

    // stage chunk c into buffer buf: 4 doc + 1 qn global_load_lds per thread.
    // doc: 1024 16B-slots; slot S=i*256+tid -> row r=S>>3, phys slot p=S&7
    //      holds logical slot p^(r&7) (inverse-swizzled source, linear dest).
    // qn:  waves 0,1 stage qh's 128 slots; waves 2,3 stage ql's; slot s ->
    //      q=s>>2, phys p=s&3 holds logical p^(q&3) (8 bf16 per slot).
    auto STAGE = [&](int c, int buf) {
        #pragma unroll
        for (int i = 0; i < 4; ++i) {
            int S  = i * 256 + tid;
            int r  = S >> 3;
            int lg = (S & 7) ^ (r & 7);
            int kk = c * KC + 4 * lg;
            if (kk >= EE) kk = 0;         // pad slot: redirect in-bounds (qn pad=0)
            __builtin_amdgcn_global_load_lds(
                (const __attribute__((address_space(1))) void*)(docb + (size_t)r * EE + kk),
                (__attribute__((address_space(3))) void*)&s_doc[buf][(i * 256 + wv * 64) * 4],
                16, 0, 0);
        }
        if (wv < 2) {
            int s  = wv * 64 + td;        // qh slot
            int q  = s >> 2;
            int lg = (s & 3) ^ (q & 3);
            __builtin_amdgcn_global_load_lds(
                (const __attribute__((address_space(1))) void*)
                    (qhb + (size_t)q * EPAD + c * KC + 8 * lg),
                (__attribute__((address_space(3))) void*)&s_qh[buf][wv * 512],
                16, 0, 0);
        } else {
            int s  = (wv - 2) * 64 + td;  // ql slot
            int q  = s >> 2;
            int lg = (s & 3) ^ (q & 3);
            __builtin_amdgcn_global_load_lds(
                (const __attribute__((address_space(1))) void*)
                    (qlb + (size_t)q * EPAD + c * KC + 8 * lg),
                (__attribute__((address_space(3))) void*)&s_ql[buf][(wv - 2) * 512],
                16, 0, 0);
        }
    };

    STAGE(0, 0);

    f32x4 acc[2][2];
    #pragma unroll
    for (int qt = 0; qt < 2; ++qt)
        #pragma unroll
        for (int t = 0; t < 2; ++t) acc[qt][t] = (f32x4){0.f, 0.f, 0.f, 0.f};
    float ssq[2] = {0.f, 0.f};

    int cur = 0;
    for (int c = 0; c < NCH; ++c) {
        if (c + 1 < NCH) {
            STAGE(c + 1, cur ^ 1);
            asm volatile("s_waitcnt vmcnt(5)" ::: "memory");
        } else {
            asm volatile("s_waitcnt vmcnt(0)" ::: "memory");
        }
        __builtin_amdgcn_s_barrier();

        // A fragments (qn hi/lo) for this chunk: logical slot l4, phys l4^(q&3)
        short8v ah[2], al[2];
        #pragma unroll
        for (int qt = 0; qt < 2; ++qt) {
            if (qt < nqt) {
                const int qrow = qt * 16 + l15;
                const int p = l4 ^ (qrow & 3);
                ah[qt] = *(const short8v*)&s_qh[cur][qrow * KC + p * 8];
                al[qt] = *(const short8v*)&s_ql[cur][qrow * KC + p * 8];
            }
        }

        const int kb = c * KC + l4 * 8;
        const bool r1 = (kb < EE), r2 = (kb + 4 < EE);   // real (non-pad) quads

        #pragma unroll
        for (int t = 0; t < 2; ++t) {
            const int lrow = wv * 32 + t * 16 + l15;
            const int p0 = (2 * l4)     ^ (lrow & 7);
            const int p1 = (2 * l4 + 1) ^ (lrow & 7);
            const f32x4 v0 = *(const f32x4*)&s_doc[cur][lrow * KC + p0 * 4];
            const f32x4 v1 = *(const f32x4*)&s_doc[cur][lrow * KC + p1 * 4];
            if (r1) ssq[t] += v0.x * v0.x + v0.y * v0.y + v0.z * v0.z + v0.w * v0.w;
            if (r2) ssq[t] += v1.x * v1.x + v1.y * v1.y + v1.z * v1.z + v1.w * v1.w;

            short8v bhi, blo;
            #pragma unroll
            for (int j = 0; j < 4; ++j) {
                unsigned short h0 = f2bf(v0[j]);
                unsigned short h1 = f2bf(v1[j]);
                bhi[j]     = (short)h0;
                bhi[j + 4] = (short)h1;
                blo[j]     = (short)f2bf(v0[j] - bf2f(h0));
                blo[j + 4] = (short)f2bf(v1[j] - bf2f(h1));
            }
            acc[0][t] = __builtin_amdgcn_mfma_f32_16x16x32_bf16(ah[0], bhi, acc[0][t], 0, 0, 0);
            acc[0][t] = __builtin_amdgcn_mfma_f32_16x16x32_bf16(ah[0], blo, acc[0][t], 0, 0, 0);
            acc[0][t] = __builtin_amdgcn_mfma_f32_16x16x32_bf16(al[0], bhi, acc[0][t], 0, 0, 0);
            if (nqt > 1) {
                acc[1][t] = __builtin_amdgcn_mfma_f32_16x16x32_bf16(ah[1], bhi, acc[1][t], 0, 0, 0);
                acc[1][t] = __builtin_amdgcn_mfma_f32_16x16x32_bf16(ah[1], blo, acc[1][t], 0, 0, 0);
                acc[1][t] = __builtin_amdgcn_mfma_f32_16x16x32_bf16(al[1], bhi, acc[1][t], 0, 0, 0);
            }
        }
        __builtin_amdgcn_s_barrier();     // all reads done before buffer re-staged
        cur ^= 1;
    }

    // full row-norms: combine the 4 k-window partials (lanes l, l^16, l^32)
    float rinv[2];
    #pragma unroll
    for (int t = 0; t < 2; ++t) {
        float s = ssq[t];
        s += __shfl_xor(s, 16);
        s += __shfl_xor(s, 32);
        rinv[t] = 1.0f / sqrtf(s);        // row (l15) of tile t
    }

    // histogram in LDS, aliasing s_doc (dead after the loop's final barrier)
    int* hist = (int*)&s_doc[0][0];       // [QQ][32]
    for (int s = tid; s < QQ * 32; s += 256) hist[s] = 0;
    __syncthreads();

    // D layout (m89-verified): col = lane&15 (= d in tile), row = (lane>>4)*4 + reg (= q)
    #pragma unroll
    for (int qt = 0; qt < 2; ++qt) {
        #pragma unroll
        for (int r = 0; r < 4; ++r) {
            const int q = qt * 16 + l4 * 4 + r;
            if (q < len) {
                #pragma unroll
                for (int t = 0; t < 2; ++t) {
                    float sim = acc[qt][t][r] * rinv[t];
                    int bin = (int)floorf((sim + 1.0f) * 15.0f);
                    bin = bin < 0 ? 0 : (bin > 29 ? 29 : bin);
                    atomicAdd(&hist[q * 32 + bin], 1);
                }
            }
        }
    }
    __syncthreads();

    for (int s = tid; s < QQ * NB; s += 256) {
        const int q = s / NB, bin = s % NB;
        int tot = hist[q * 32 + bin];
        if (tot) atomicAdd(&ghist[((size_t)b * QQ + q) * NB + bin], tot);
    }
}

// ---------------- final: log1p + FFN + softmax gate + weighted sum ----------------
__global__ __launch_bounds__(64) void drmm_final(const int* __restrict__ ghist,
                                                 const float* __restrict__ glog,
                                                 const float* __restrict__ W1,
                                                 const float* __restrict__ b1,
                                                 const float* __restrict__ W2,
                                                 const float* __restrict__ b2,
                                                 const float* __restrict__ W3,
                                                 const float* __restrict__ b3,
                                                 float* __restrict__ out) {
    const int b = blockIdx.x;
    const int lane = threadIdx.x;         // lanes 0..31 carry q
    float z = 0.f, lg = -1e30f;
    if (lane < QQ) {
        const int* hrow = ghist + ((size_t)b * QQ + lane) * NB;
        float h[NB];
        #pragma unroll
        for (int v = 0; v < NB; ++v) h[v] = log1pf((float)hrow[v]);
        float t1[5];
        #pragma unroll
        for (int u = 0; u < 5; ++u) {
            float s = b1[u];
            #pragma unroll
            for (int v = 0; v < NB; ++v) s += W1[u * NB + v] * h[v];
            t1[u] = tanhf(s);
        }
        float s2 = b2[0];
        #pragma unroll
        for (int u = 0; u < 5; ++u) s2 += W2[u] * t1[u];
        z = tanhf(W3[0] * tanhf(s2) + b3[0]);
        lg = glog[b * QQ + lane];
    }
    float m = lg;
    for (int o = 16; o >= 1; o >>= 1) m = fmaxf(m, __shfl_xor(m, o));
    float e = (lane < QQ) ? expf(lg - m) : 0.f;
    float s = e;
    for (int o = 16; o >= 1; o >>= 1) s += __shfl_xor(s, o);
    float w = z * (e / s);
    for (int o = 16; o >= 1; o >>= 1) w += __shfl_xor(w, o);
    if (lane == 0) out[b] = w;
}

extern "C" void kernel_launch(void* const* d_in, const int* in_sizes, int n_in,
                              void* d_out, int out_size, void* d_ws, size_t ws_size,
                              hipStream_t stream) {
    const float* query = (const float*)d_in[0];
    const float* doc   = (const float*)d_in[1];
    const int*   qlen  = (const int*)d_in[2];
    const float* W1    = (const float*)d_in[3];
    const float* b1    = (const float*)d_in[4];
    const float* W2    = (const float*)d_in[5];
    const float* b2    = (const float*)d_in[6];
    const float* W3    = (const float*)d_in[7];
    const float* b3    = (const float*)d_in[8];
    const float* Wg    = (const float*)d_in[9];
    const float* bg    = (const float*)d_in[10];
    float* out = (float*)d_out;

    unsigned short* qh = (unsigned short*)d_ws;            // [2048][320] bf16 hi
    unsigned short* ql = qh + (size_t)BB * QQ * EPAD;      // [2048][320] bf16 lo
    float* glog = (float*)(ql + (size_t)BB * QQ * EPAD);   // [2048]
    int*   hist = (int*)(glog + BB * QQ);                  // [64][32][30]

    hipLaunchKernelGGL(drmm_prep, dim3(BB * QQ), dim3(64), 0, stream,
                       query, Wg, bg, qh, ql, glog, hist);
    hipLaunchKernelGGL(drmm_main, dim3(BB * NDT), dim3(256), 0, stream,
                       doc, qlen, qh, ql, hist);
    hipLaunchKernelGGL(drmm_final, dim3(BB), dim3(64), 0, stream,
                       hist, glog, W1, b1, W2, b2, W3, b3, out);
}